// Round 5
// baseline (229.026 us; speedup 1.0000x reference)
//
#include <hip/hip_runtime.h>

// SparseMCFModel — flow depends only on demands/edge_row/edge_col (GAT/GRU dead).
//   V_1[v] = relu(d[v])/deg[v]
//   V_j[v] = (relu(d[v]) + sum_{e:col=v} V_{j-1}[row_e]) / deg[v],  j=2..10
//   out[e] = V_10[row_e]
//
// r19: fused single dispatch, full-machine grid (256 blk x 256 thr, 1 blk/CU).
//  POST-MORTEM r17/r18: flow_k 56.8us invariant across {coherent vs cached
//  gather} and {40 vs 80 blocks} -> rounds are sync-ladder + too-few-CU bound,
//  not gather-path bound. Fix: all phases on 256 CUs, dispatch count back to 2.
//  - Build in-kernel with PLAIN pcsc stores + fence(release,"agent") before
//    the barrier (writeback dirty L2); readers use proven gbar+acquire-fence
//    (r18: absmax 0.0). Kills r14's 19MB write-through.
//  - One node per thread (79/block), branch-free 24-slot cached gathers
//    (pad slots -> zeroed V[N_NODES] line, +0.0f bitwise-neutral).
//  - V2 direct from inputs (saves a round); 10 gbars total; out written from
//    build-phase r4 registers (no edge_row re-read).
//  - gbar: 256 arrivals over 32 padded lines (8 serialized RMWs each);
//    watchdog-bounded spins only (any anomaly -> wrong numbers, never hang).

#define N_NODES 20000
#define N_EDGES 200000
#define NTHR 256
#define NBLK 256
#define QPB 196                            // quads/block: 196*256 = 50176 >= 50000
#define NPB 79                             // nodes/block: 79*256  = 20224 >= 20000
#define CAP 24                             // padded in-edge slots per node
#define NQUAD 50000                        // N_EDGES/4 int4 quads
#define OFL_MAX 4096
#define NP1 (N_NODES + 1)                  // V arrays: zero pad at [N_NODES]
#define SPIN_MAX 65536                     // watchdog
#define NLINE 32                           // arrival counter lines

__device__ __forceinline__ void st_coh(float* p, float v) {
    __hip_atomic_store(p, v, __ATOMIC_RELAXED, __HIP_MEMORY_SCOPE_AGENT);
}
__device__ __forceinline__ void acq_fence() {
    __builtin_amdgcn_fence(__ATOMIC_ACQUIRE, "agent");   // inv stale L1/L2
}
__device__ __forceinline__ void rel_fence() {
    __builtin_amdgcn_fence(__ATOMIC_RELEASE, "agent");   // wb dirty lines
}

// Distributed-arrival barrier: 256 arrivals over 32 padded lines (8 serialized
// RMWs each, lines in parallel); poller sums 32 independent loads.
__device__ __forceinline__ void gbar(int* grp, int ord) {
    __syncthreads();
    if (threadIdx.x == 0) {
        __hip_atomic_fetch_add(&grp[(blockIdx.x & (NLINE - 1)) * 32], 1,
                               __ATOMIC_RELAXED, __HIP_MEMORY_SCOPE_AGENT);
        const int target = NBLK * ord;
        for (int t = 0; t < SPIN_MAX; ++t) {
            int s = 0;
            #pragma unroll
            for (int g = 0; g < NLINE; ++g)
                s += __hip_atomic_load(&grp[g * 32], __ATOMIC_RELAXED,
                                       __HIP_MEMORY_SCOPE_AGENT);
            if (s >= target) break;
            __builtin_amdgcn_s_sleep(1);
        }
    }
    __syncthreads();
}

__global__ __launch_bounds__(NTHR)
void mcf_fused(const float* __restrict__ demands,
               const int* __restrict__ edge_row,   // int4-aligned
               const int* __restrict__ edge_col,
               float* __restrict__ out,
               int* __restrict__ deg,       // [N]        zeroed
               int* __restrict__ fill,      // [N]        zeroed
               float* __restrict__ V0,      // [NP1]      zeroed (pad = 0)
               float* __restrict__ V1b,     // [NP1]      zeroed (pad = 0)
               int* __restrict__ pcsc,      // [N*CAP]    uninit
               int* __restrict__ ofl_cnt,   // [1]        zeroed
               int* __restrict__ ofl_v,     // [OFL_MAX]  uninit
               int* __restrict__ ofl_row,   // [OFL_MAX]  uninit
               int* __restrict__ grp)       // [NLINE*32] zeroed
{
    const int tx = threadIdx.x, bx = blockIdx.x;
    int bar = 0;

    // ---- Build: counters via agent RMW, pcsc/overflow via PLAIN stores ----
    const int m = bx * QPB + tx;
    const bool bld = (tx < QPB) && (m < NQUAD);
    int4 r4 = {0, 0, 0, 0};
    if (bld) {
        r4 = ((const int4*)edge_row)[m];
        int4 c4 = ((const int4*)edge_col)[m];
        int rr[4] = {r4.x, r4.y, r4.z, r4.w};
        int cc[4] = {c4.x, c4.y, c4.z, c4.w};
        #pragma unroll
        for (int i = 0; i < 4; ++i) {
            __hip_atomic_fetch_add(&deg[rr[i]], 1,
                                   __ATOMIC_RELAXED, __HIP_MEMORY_SCOPE_AGENT);
            int idx = __hip_atomic_fetch_add(&fill[cc[i]], 1,
                                             __ATOMIC_RELAXED, __HIP_MEMORY_SCOPE_AGENT);
            if (idx < CAP) {
                pcsc[cc[i] * CAP + idx] = rr[i];           // plain, L2-coalesced
            } else {
                int o = __hip_atomic_fetch_add(ofl_cnt, 1,
                                               __ATOMIC_RELAXED, __HIP_MEMORY_SCOPE_AGENT);
                if (o < OFL_MAX) { ofl_v[o] = cc[i]; ofl_row[o] = rr[i]; }
            }
        }
    }
    rel_fence();                 // writeback plain stores before signaling
    gbar(grp, ++bar);
    acq_fence();                 // invalidate stale copies before plain reads

    // ---- Owner setup + V2 direct from inputs ----
    const int v = bx * NPB + tx;
    const bool own = (tx < NPB) && (v < N_NODES);
    int   er[CAP];
    int   cnt = 0, ocnt = 0;
    float dposv = 0.0f, invd = 0.0f;
    if (own) {
        cnt = min(fill[v], CAP);                    // plain cached post-fence
        const int4* pb = (const int4*)&pcsc[v * CAP];
        #pragma unroll
        for (int q = 0; q < 6; ++q) {
            int4 a = pb[q];
            er[q * 4 + 0] = a.x; er[q * 4 + 1] = a.y;
            er[q * 4 + 2] = a.z; er[q * 4 + 3] = a.w;
        }
        dposv = fmaxf(demands[v], 0.0f);
        invd  = (deg[v] > 0) ? (1.0f / (float)deg[v]) : 0.0f;
        ocnt  = *ofl_cnt;                           // expected ~0

        // V2[v] = (dpos[v] + sum_s relu(d[er_s])/deg[er_s]) * invd
        float acc = dposv;
        #pragma unroll
        for (int s = 0; s < CAP; ++s)
            if (s < cnt)
                acc += fmaxf(demands[er[s]], 0.0f) * (1.0f / (float)deg[er[s]]);
        if (ocnt > 0) {
            for (int o = 0; o < ocnt && o < OFL_MAX; ++o)
                if (ofl_v[o] == v) {
                    int r = ofl_row[o];
                    acc += fmaxf(demands[r], 0.0f) * (1.0f / (float)deg[r]);
                }
        }
        st_coh(&V0[v], acc * invd);                 // publish V2 (write-through)

        // pad unused slots -> index N_NODES (V*[N_NODES] = 0.0 from memset)
        #pragma unroll
        for (int s = 0; s < CAP; ++s)
            if (s >= cnt) er[s] = N_NODES;
    }
    gbar(grp, ++bar);
    acq_fence();

    // ---- rounds j=3..10: plain cached 24-wide gather, coherent publish ----
    #pragma unroll 1
    for (int j = 3; j <= 10; ++j) {
        const float* Vp = (j & 1) ? V0 : V1b;   // j odd reads V0 (even level)
        float*       Vn = (j & 1) ? V1b : V0;
        if (own) {
            float t[CAP];
            #pragma unroll
            for (int s = 0; s < CAP; ++s)
                t[s] = Vp[er[s]];               // plain: L1/L2 hit post-fence
            float acc = dposv;
            #pragma unroll
            for (int s = 0; s < CAP; ++s)       // deterministic slot order
                acc += t[s];
            if (ocnt > 0) {                     // exactness fallback, ~never
                for (int o = 0; o < ocnt && o < OFL_MAX; ++o)
                    if (ofl_v[o] == v) acc += Vp[ofl_row[o]];
            }
            st_coh(&Vn[v], acc * invd);         // write-through publish
        }
        gbar(grp, ++bar);
        acq_fence();
    }

    // ---- out[e] = V_10[row_e] (j=10 wrote V0); r4 still in registers ----
    if (bld) {
        float4 o4;
        o4.x = V0[r4.x];
        o4.y = V0[r4.y];
        o4.z = V0[r4.z];
        o4.w = V0[r4.w];
        ((float4*)out)[m] = o4;
    }
}

extern "C" void kernel_launch(void* const* d_in, const int* in_sizes, int n_in,
                              void* d_out, int out_size, void* d_ws, size_t ws_size,
                              hipStream_t stream) {
    const float* demands  = (const float*)d_in[1];
    const int*   edge_row = (const int*)d_in[2];
    const int*   edge_col = (const int*)d_in[3];
    float*       out      = (float*)d_out;

    char* ws = (char*)d_ws;
    auto take = [&](size_t bytes) {
        void* p = (void*)ws;
        ws += (bytes + 127) & ~size_t(127);
        return p;
    };
    // ---- zero zone (one 0x00 memset) ----
    char* zone0 = ws;
    int*   deg     = (int*)  take(N_NODES * 4);
    int*   fill    = (int*)  take(N_NODES * 4);
    float* V0      = (float*)take(NP1 * 4);
    float* V1b     = (float*)take(NP1 * 4);
    int*   ofl_cnt = (int*)  take(4);
    int*   grp     = (int*)  take(NLINE * 32 * 4);
    size_t zone0_bytes = (size_t)(ws - zone0);
    // ---- uninitialized zone ----
    int*   pcsc    = (int*)  take((size_t)N_NODES * CAP * 4);
    int*   ofl_v   = (int*)  take(OFL_MAX * 4);
    int*   ofl_row = (int*)  take(OFL_MAX * 4);

    hipMemsetAsync(zone0, 0x00, zone0_bytes, stream);
    mcf_fused<<<NBLK, NTHR, 0, stream>>>(demands, edge_row, edge_col, out,
                                         deg, fill, V0, V1b, pcsc,
                                         ofl_cnt, ofl_v, ofl_row, grp);
}

// Round 6
// 158.026 us; speedup vs baseline: 1.4493x; 1.4493x over previous
//
#include <hip/hip_runtime.h>

// SparseMCFModel — flow depends only on demands/edge_row/edge_col (GAT/GRU dead).
//   V_1[v] = relu(d[v])/deg[v]
//   V_j[v] = (relu(d[v]) + sum_{e:col=v} V_{j-1}[row_e]) / deg[v],  j=2..10
//   out[e] = V_10[row_e]
//
// r20 = r14 skeleton (best measured round structure, ~3.5us/round) + two
// independently-proven deltas:
//  (1) V2-direct in setup (r15-r19 bitwise-proven): role-split sum of
//      relu(d[er])/deg[er], same grouping/order as rounds -> 8 rounds, 10 gbars.
//  (2) plain-store build + ONE rel/acq fence pair at the build boundary
//      (r19 bitwise-proven handoff): kills 20.5MB write-through + the ~14
//      write-ACK vmcnt drain per build lane at the first barrier.
//  POST-MORTEM r19: per-round fences are L2 wbinv broadcasts (~8us/round) —
//  fences appear EXACTLY ONCE here. Rounds keep r14's ld_coh gather (L2-bypass,
//  no staleness, no fences) + st_coh publish.
//  POST-MORTEM r17/r18: 56.8us invariant to gather path & 40/80 blocks ->
//  128-block role structure retained unchanged.

#define N_NODES 20000
#define N_EDGES 200000
#define NBLK 128
#define NTHR 512
#define NPB 157                            // nodes per block (128*157 = 20096)
#define CAP 24                             // padded in-edge slots per node
#define NQUAD 50000                        // N_EDGES/4 int4 quads
#define QPB 391                            // quads per block (391*128 = 50048)
#define OFL_MAX 4096
#define NP1 (N_NODES + 1)
#define SPIN_MAX 65536                     // watchdog: never hang, go wrong loud
#define NLINE 16                           // arrival counter lines

__device__ __forceinline__ float ld_coh(const float* p) {
    return __hip_atomic_load(p, __ATOMIC_RELAXED, __HIP_MEMORY_SCOPE_AGENT);
}
__device__ __forceinline__ void st_coh(float* p, float v) {
    __hip_atomic_store(p, v, __ATOMIC_RELAXED, __HIP_MEMORY_SCOPE_AGENT);
}
__device__ __forceinline__ void acq_fence() {
    __builtin_amdgcn_fence(__ATOMIC_ACQUIRE, "agent");   // inv stale L1/L2
}
__device__ __forceinline__ void rel_fence() {
    __builtin_amdgcn_fence(__ATOMIC_RELEASE, "agent");   // wb dirty L2 lines
}

// Distributed-arrival barrier: 128 arrivals over 16 padded lines (8 serialized
// RMWs each, lines in parallel); poller sums 16 independent loads. Watchdog.
__device__ __forceinline__ void gbar(int* grp, int ord) {
    __syncthreads();
    if (threadIdx.x == 0) {
        __hip_atomic_fetch_add(&grp[(blockIdx.x & (NLINE - 1)) * 32], 1,
                               __ATOMIC_RELAXED, __HIP_MEMORY_SCOPE_AGENT);
        const int target = NBLK * ord;
        for (int t = 0; t < SPIN_MAX; ++t) {
            int s = 0;
            #pragma unroll
            for (int g = 0; g < NLINE; ++g)
                s += __hip_atomic_load(&grp[g * 32], __ATOMIC_RELAXED,
                                       __HIP_MEMORY_SCOPE_AGENT);
            if (s >= target) break;
            __builtin_amdgcn_s_sleep(1);
        }
    }
    __syncthreads();
}

__global__ __launch_bounds__(NTHR)
void mcf_fused(const float* __restrict__ demands,
               const int* __restrict__ edge_row,   // int4-aligned
               const int* __restrict__ edge_col,
               float* __restrict__ out,
               int* __restrict__ deg,       // [N]        zeroed
               int* __restrict__ fill,      // [N]        zeroed
               float* __restrict__ V0,      // [NP1]      zeroed (pad = 0)
               float* __restrict__ V1b,     // [NP1]      zeroed (pad = 0)
               int* __restrict__ pcsc,      // [N*CAP]    uninit
               int* __restrict__ ofl_cnt,   // [1]        zeroed
               int* __restrict__ ofl_v,     // [OFL_MAX]  uninit
               int* __restrict__ ofl_row,   // [OFL_MAX]  uninit
               int* __restrict__ grp)       // [NLINE*32] zeroed
{
    const int tx = threadIdx.x, bx = blockIdx.x;
    int bar = 0;

    __shared__ float part[NTHR];

    // ---- Build: counters via agent RMW, pcsc/overflow via PLAIN stores ----
    const int m = bx * QPB + tx;                  // this thread's quad
    const bool bld = (tx < QPB) && (m < NQUAD);
    int4 r4 = {0, 0, 0, 0};
    if (bld) {
        r4 = ((const int4*)edge_row)[m];
        int4 c4 = ((const int4*)edge_col)[m];
        int rr[4] = {r4.x, r4.y, r4.z, r4.w};
        int cc[4] = {c4.x, c4.y, c4.z, c4.w};
        #pragma unroll
        for (int i = 0; i < 4; ++i) {
            __hip_atomic_fetch_add(&deg[rr[i]], 1,
                                   __ATOMIC_RELAXED, __HIP_MEMORY_SCOPE_AGENT);
            int idx = __hip_atomic_fetch_add(&fill[cc[i]], 1,
                                             __ATOMIC_RELAXED, __HIP_MEMORY_SCOPE_AGENT);
            if (idx < CAP) {
                pcsc[cc[i] * CAP + idx] = rr[i];           // plain, L2-merged
            } else {
                int o = __hip_atomic_fetch_add(ofl_cnt, 1,
                                               __ATOMIC_RELAXED, __HIP_MEMORY_SCOPE_AGENT);
                if (o < OFL_MAX) { ofl_v[o] = cc[i]; ofl_row[o] = rr[i]; }
            }
        }
    }
    rel_fence();                 // ONE writeback of plain stores (r19-proven)
    gbar(grp, ++bar);
    acq_fence();                 // ONE invalidate before plain reads

    // ---- Role setup: g = node-in-block, q = role (slots q*8..q*8+7) ----
    const int g = tx / 3, q = tx - 3 * g;
    const int v = bx * NPB + g;
    const bool active = (g < NPB) && (v < N_NODES);
    float dposv = 0.0f, invd = 0.0f;
    int   cnt = 0, ocnt = 0;
    int   er[8];
    if (active) {
        cnt = min(fill[v], CAP);                        // plain, post-fence
        const int4* pb = (const int4*)&pcsc[v * CAP + q * 8];
        int4 a = pb[0], b = pb[1];                      // plain, post-fence
        er[0]=a.x; er[1]=a.y; er[2]=a.z; er[3]=a.w;
        er[4]=b.x; er[5]=b.y; er[6]=b.z; er[7]=b.w;
        if (q == 0) {
            dposv  = fmaxf(demands[v], 0.0f);
            int dv = deg[v];                            // plain, post-fence
            invd   = (dv > 0) ? (1.0f / (float)dv) : 0.0f;
            ocnt   = *ofl_cnt;                          // expected 0
        }
        // -- V2-direct: role partial of sum relu(d[er_s])/deg[er_s] --
        float p = 0.0f;
        #pragma unroll
        for (int s = 0; s < 8; ++s)
            if (q * 8 + s < cnt)
                p += fmaxf(demands[er[s]], 0.0f) * (1.0f / (float)deg[er[s]]);
        part[tx] = p;
    }
    __syncthreads();
    if (active && q == 0) {
        float acc = dposv + part[tx] + part[tx + 1] + part[tx + 2];
        if (ocnt > 0) {                                 // exactness fallback
            for (int o = 0; o < ocnt && o < OFL_MAX; ++o)
                if (ofl_v[o] == v) {
                    int r = ofl_row[o];
                    acc += fmaxf(demands[r], 0.0f) * (1.0f / (float)deg[r]);
                }
        }
        st_coh(&V0[v], acc * invd);                     // publish V2
    }
    gbar(grp, ++bar);

    // ---- 8 rounds j=3..10: predicated role gathers + LDS 3-way reduce ----
    #pragma unroll 1
    for (int j = 3; j <= 10; ++j) {
        const float* Vp = (j & 1) ? V0 : V1b;   // j odd reads V0 (even level)
        float*       Vn = (j & 1) ? V1b : V0;
        if (active) {
            float p = 0.0f;
            #pragma unroll
            for (int s = 0; s < 8; ++s)
                if (q * 8 + s < cnt) p += ld_coh(&Vp[er[s]]);   // predicated
            part[tx] = p;
        }
        __syncthreads();
        if (active && q == 0) {
            float acc = dposv + part[tx] + part[tx + 1] + part[tx + 2];
            if (ocnt > 0) {                     // exactness fallback, ~never
                for (int o = 0; o < ocnt && o < OFL_MAX; ++o)
                    if (ofl_v[o] == v) acc += ld_coh(&Vp[ofl_row[o]]);
            }
            st_coh(&Vn[v], acc * invd);         // publish V_j
        }
        gbar(grp, ++bar);
    }

    // ---- out[e] = V_10[row_e] (j=10 wrote V0); r4 in registers ----
    if (bld) {
        float4 o4;
        o4.x = ld_coh(&V0[r4.x]);
        o4.y = ld_coh(&V0[r4.y]);
        o4.z = ld_coh(&V0[r4.z]);
        o4.w = ld_coh(&V0[r4.w]);
        ((float4*)out)[m] = o4;
    }
}

extern "C" void kernel_launch(void* const* d_in, const int* in_sizes, int n_in,
                              void* d_out, int out_size, void* d_ws, size_t ws_size,
                              hipStream_t stream) {
    const float* demands  = (const float*)d_in[1];
    const int*   edge_row = (const int*)d_in[2];
    const int*   edge_col = (const int*)d_in[3];
    float*       out      = (float*)d_out;

    char* ws = (char*)d_ws;
    auto take = [&](size_t bytes) {
        void* p = (void*)ws;
        ws += (bytes + 127) & ~size_t(127);
        return p;
    };
    // ---- zero zone (one 0x00 memset) ----
    char* zone0 = ws;
    int*   deg     = (int*)  take(N_NODES * 4);
    int*   fill    = (int*)  take(N_NODES * 4);
    float* V0      = (float*)take(NP1 * 4);
    float* V1b     = (float*)take(NP1 * 4);
    int*   ofl_cnt = (int*)  take(4);
    int*   grp     = (int*)  take(NLINE * 32 * 4);
    size_t zone0_bytes = (size_t)(ws - zone0);
    // ---- uninitialized zone ----
    int*   pcsc    = (int*)  take((size_t)N_NODES * CAP * 4);
    int*   ofl_v   = (int*)  take(OFL_MAX * 4);
    int*   ofl_row = (int*)  take(OFL_MAX * 4);

    hipMemsetAsync(zone0, 0x00, zone0_bytes, stream);
    mcf_fused<<<NBLK, NTHR, 0, stream>>>(demands, edge_row, edge_col, out,
                                         deg, fill, V0, V1b, pcsc,
                                         ofl_cnt, ofl_v, ofl_row, grp);
}

// Round 7
// 121.228 us; speedup vs baseline: 1.8892x; 1.3035x over previous
//
#include <hip/hip_runtime.h>

// SparseMCFModel — flow depends only on demands/edge_row/edge_col (GAT/GRU dead).
//   V_1[v] = relu(d[v])/deg[v]
//   V_j[v] = (relu(d[v]) + sum_{e:col=v} V_{j-1}[row_e]) / deg[v],  j=2..10
//   out[e] = V_10[row_e]
//
// r21 = r14 EXACT skeleton (50.2us measured optimum) + ONE fence-free delta:
//   V2-direct setup (r20 bitwise-proven, absmax 0.0): the j=2 round's V1
//   gather is replaced by gathering deg[er]/demands[er] directly and summing
//   relu(d[er_s])*(1/deg[er_s]) — each term identical to the V1 the source's
//   owner would publish; same role-split partial order. 11 gbars -> 10,
//   9 rounds -> 8.
// POST-MORTEM series (why nothing else changed):
//   r15/r16: multi-level dataflow convoys (~7us/level) — barriers win.
//   r17/r18: small-grid 1-thr/node flow_k 56.8us invariant to gather path
//            and 40/80 blocks — r14's 128-block role structure is better.
//   r19:     per-round agent fences = L2 wbinv broadcast storms (154us).
//   r20:     even ONE fence pair from all waves costs ~+37us; plain-store
//            build saves NO write traffic (pcsc scatter dirties ~12MB across
//            8 non-coherent L2s -> ~19MB writeback either way). Fences: zero.
// Coherence rules (r6-r14 proven): cross-block mutable data ONLY via
// agent-scope atomic ld/st (MALL-coherent); deg/fill MUST be read ld_coh
// (memset may leave stale-zero L2 copies); pcsc written st_coh and read
// plain (lines fresh this dispatch, never read pre-barrier); demands/edge_*
// are immutable inputs -> plain cached. All spins watchdog-bounded.

#define N_NODES 20000
#define N_EDGES 200000
#define NBLK 128
#define NTHR 512
#define NPB 157                            // nodes per block (128*157 = 20096)
#define CAP 24                             // padded in-edge slots per node
#define NQUAD 50000                        // N_EDGES/4 int4 quads
#define QPB 391                            // quads per block (391*128 = 50048)
#define OFL_MAX 4096
#define NP1 (N_NODES + 1)
#define SPIN_MAX 65536                     // watchdog: never hang, fail loud

__device__ __forceinline__ float ld_coh(const float* p) {
    return __hip_atomic_load(p, __ATOMIC_RELAXED, __HIP_MEMORY_SCOPE_AGENT);
}
__device__ __forceinline__ int ld_coh_i(const int* p) {
    return __hip_atomic_load(p, __ATOMIC_RELAXED, __HIP_MEMORY_SCOPE_AGENT);
}
__device__ __forceinline__ void st_coh(float* p, float v) {
    __hip_atomic_store(p, v, __ATOMIC_RELAXED, __HIP_MEMORY_SCOPE_AGENT);
}
__device__ __forceinline__ void st_coh_i(int* p, int v) {
    __hip_atomic_store(p, v, __ATOMIC_RELAXED, __HIP_MEMORY_SCOPE_AGENT);
}

// Distributed-arrival barrier (r14-exact): 8 padded lines, 16 serialized RMWs
// each (lines in parallel); poller sums all 8 with ILP. Watchdog-bounded.
__device__ __forceinline__ void gbar(int* grp, int ord) {
    __syncthreads();
    if (threadIdx.x == 0) {
        __hip_atomic_fetch_add(&grp[(blockIdx.x & 7) * 32], 1,
                               __ATOMIC_RELAXED, __HIP_MEMORY_SCOPE_AGENT);
        const int target = NBLK * ord;
        for (int t = 0; t < SPIN_MAX; ++t) {
            int s = 0;
            #pragma unroll
            for (int g = 0; g < 8; ++g)
                s += __hip_atomic_load(&grp[g * 32], __ATOMIC_RELAXED,
                                       __HIP_MEMORY_SCOPE_AGENT);
            if (s >= target) break;
            __builtin_amdgcn_s_sleep(1);
        }
    }
    __syncthreads();
}

__global__ __launch_bounds__(NTHR)
void mcf_fused(const float* __restrict__ demands,
               const int* __restrict__ edge_row,   // int4-aligned
               const int* __restrict__ edge_col,
               float* __restrict__ out,
               int* __restrict__ deg,       // [N]   zeroed
               int* __restrict__ fill,      // [N]   zeroed
               float* __restrict__ V0,      // [N+1] zeroed
               float* __restrict__ V1b,     // [N+1] zeroed
               int* __restrict__ pcsc,      // [N*CAP]
               int* __restrict__ ofl_cnt,   // [1]   zeroed
               int* __restrict__ ofl_v,     // [OFL_MAX]
               int* __restrict__ ofl_row,   // [OFL_MAX]
               int* __restrict__ grp)       // [8*32] zeroed
{
    const int tx = threadIdx.x, bx = blockIdx.x;
    int bar = 0;

    __shared__ float part[NTHR];

    // ---- Build (r14-exact): int4 edge loads, deg/fill atomics, st_coh pcsc ----
    const int m = bx * QPB + tx;                  // this thread's quad
    const bool bld = (tx < QPB) && (m < NQUAD);
    int4 r4 = {0, 0, 0, 0};
    if (bld) {
        r4 = ((const int4*)edge_row)[m];
        int4 c4 = ((const int4*)edge_col)[m];
        int rr[4] = {r4.x, r4.y, r4.z, r4.w};
        int cc[4] = {c4.x, c4.y, c4.z, c4.w};
        #pragma unroll
        for (int i = 0; i < 4; ++i) {
            __hip_atomic_fetch_add(&deg[rr[i]], 1, __ATOMIC_RELAXED, __HIP_MEMORY_SCOPE_AGENT);
            int idx = __hip_atomic_fetch_add(&fill[cc[i]], 1,
                                             __ATOMIC_RELAXED, __HIP_MEMORY_SCOPE_AGENT);
            if (idx < CAP) {
                st_coh_i(&pcsc[cc[i] * CAP + idx], rr[i]);   // 2-line-local
            } else {
                int o = __hip_atomic_fetch_add(ofl_cnt, 1,
                                               __ATOMIC_RELAXED, __HIP_MEMORY_SCOPE_AGENT);
                if (o < OFL_MAX) { st_coh_i(&ofl_v[o], cc[i]); st_coh_i(&ofl_row[o], rr[i]); }
            }
        }
    }
    gbar(grp, ++bar);

    // ---- Role setup + V2-direct (replaces the V1 publish round) ----
    const int g = tx / 3, q = tx - 3 * g;
    const int v = bx * NPB + g;
    const bool active = (g < NPB) && (v < N_NODES);
    float dposv = 0.0f, invd = 0.0f;
    int   cnt = 0, ocnt = 0;
    int   er[8];
    if (active) {
        cnt = min(ld_coh_i(&fill[v]), CAP);
        // two int4 plain loads; 32B-aligned; lines fresh (st_coh-written,
        // never read pre-barrier) -> cannot be cached stale
        const int4* pb = (const int4*)&pcsc[v * CAP + q * 8];
        int4 a = pb[0], b = pb[1];
        er[0]=a.x; er[1]=a.y; er[2]=a.z; er[3]=a.w;
        er[4]=b.x; er[5]=b.y; er[6]=b.z; er[7]=b.w;
        if (q == 0) {
            dposv  = fmaxf(demands[v], 0.0f);
            int dv = ld_coh_i(&deg[v]);
            invd   = (dv > 0) ? (1.0f / (float)dv) : 0.0f;  // V[v] unread if deg==0
            ocnt   = ld_coh_i(ofl_cnt);                     // expected 0
        }
        // V2-direct role partial: sum_s relu(d[er_s]) * (1/deg[er_s]) —
        // each term == the V1 value the source's owner would have published
        // (same fmaxf * (1.0f/deg) expression); slot order == round order.
        float p = 0.0f;
        #pragma unroll
        for (int s = 0; s < 8; ++s)
            if (q * 8 + s < cnt)
                p += fmaxf(demands[er[s]], 0.0f)
                   * (1.0f / (float)ld_coh_i(&deg[er[s]]));
        part[tx] = p;
    }
    __syncthreads();
    if (active && q == 0) {
        float acc = dposv + part[tx] + part[tx + 1] + part[tx + 2];
        if (ocnt > 0) {                                 // exactness fallback
            for (int o = 0; o < ocnt && o < OFL_MAX; ++o)
                if (ld_coh_i(&ofl_v[o]) == v) {
                    int r = ld_coh_i(&ofl_row[o]);
                    acc += fmaxf(demands[r], 0.0f)
                         * (1.0f / (float)ld_coh_i(&deg[r]));
                }
        }
        st_coh(&V0[v], acc * invd);                     // publish V2
    }
    gbar(grp, ++bar);

    // ---- 8 rounds j=3..10: predicated role gathers + LDS 3-way reduce ----
    #pragma unroll 1
    for (int j = 3; j <= 10; ++j) {
        const float* Vp = (j & 1) ? V0 : V1b;   // j odd reads V0 (even level)
        float*       Vn = (j & 1) ? V1b : V0;
        if (active) {
            float p = 0.0f;
            #pragma unroll
            for (int s = 0; s < 8; ++s)
                if (q * 8 + s < cnt) p += ld_coh(&Vp[er[s]]);   // predicated
            part[tx] = p;
        }
        __syncthreads();
        if (active && q == 0) {
            float acc = dposv + part[tx] + part[tx + 1] + part[tx + 2];
            if (ocnt > 0) {                     // exactness fallback, ~never
                for (int o = 0; o < ocnt && o < OFL_MAX; ++o)
                    if (ld_coh_i(&ofl_v[o]) == v) acc += ld_coh(&Vp[ld_coh_i(&ofl_row[o])]);
            }
            st_coh(&Vn[v], acc * invd);         // publish V_j
        }
        gbar(grp, ++bar);
    }

    // ---- out[e] = V_10[row_e] (j=10 wrote V0); r4 in registers ----
    if (bld) {
        float4 o4;
        o4.x = ld_coh(&V0[r4.x]);
        o4.y = ld_coh(&V0[r4.y]);
        o4.z = ld_coh(&V0[r4.z]);
        o4.w = ld_coh(&V0[r4.w]);
        ((float4*)out)[m] = o4;
    }
}

extern "C" void kernel_launch(void* const* d_in, const int* in_sizes, int n_in,
                              void* d_out, int out_size, void* d_ws, size_t ws_size,
                              hipStream_t stream) {
    const float* demands  = (const float*)d_in[1];
    const int*   edge_row = (const int*)d_in[2];
    const int*   edge_col = (const int*)d_in[3];
    float*       out      = (float*)d_out;

    char* ws = (char*)d_ws;
    auto take = [&](size_t bytes) {
        void* p = (void*)ws;
        ws += (bytes + 127) & ~size_t(127);
        return p;
    };
    // ---- zero zone (one 0x00 memset) ----
    char* zone0 = ws;
    int*   deg     = (int*)  take(N_NODES * 4);
    int*   fill    = (int*)  take(N_NODES * 4);
    float* V0      = (float*)take(NP1 * 4);
    float* V1b     = (float*)take(NP1 * 4);
    int*   ofl_cnt = (int*)  take(4);
    int*   grp     = (int*)  take(8 * 32 * 4);
    size_t zone0_bytes = (size_t)(ws - zone0);
    // ---- uninitialized zone ----
    int*   pcsc    = (int*)  take((size_t)N_NODES * CAP * 4);
    int*   ofl_v   = (int*)  take(OFL_MAX * 4);
    int*   ofl_row = (int*)  take(OFL_MAX * 4);

    hipMemsetAsync(zone0, 0x00, zone0_bytes, stream);
    mcf_fused<<<NBLK, NTHR, 0, stream>>>(demands, edge_row, edge_col, out,
                                         deg, fill, V0, V1b, pcsc,
                                         ofl_cnt, ofl_v, ofl_row, grp);
}